// Round 2
// baseline (28491.104 us; speedup 1.0000x reference)
//
#include <hip/hip_runtime.h>
#include <hip/hip_fp16.h>
#include <stdint.h>

#define TSTEPS 512
#define BATCH  512
#define FEAT   128
#define HID    512

typedef _Float16 half8 __attribute__((ext_vector_type(8)));
typedef float    floatx4 __attribute__((ext_vector_type(4)));

#define NCH1 20              // K chunks cell1 (640/32)
#define NCH2 32              // K chunks cell2 (1024/32)
#define W1RES_B 81920        // NCH1*4*64*16 bytes
#define W2RES_B 131072       // NCH2*4*64*16 bytes
#define RING_B  8192         // 128 rows * 64 B per chunk slot
#define SMEM_B  (W2RES_B + 3*RING_B)   // 155648 <= 163840

// ---------------- ws layout (bytes) ----------------
#define OFF_W1F  0u
#define OFF_W2F  2621440u    // 2048*640*2
#define OFF_B1   6815744u    // + 2048*1024*2
#define OFF_B2   6823936u
#define OFF_H1   6832128u    // 2 parity * 512*512 * f16 = 1 MB
#define OFF_H2   7880704u
#define OFF_CNT1 8929280u    // 512*4 ints
#define OFF_CNT2 8937472u
#define WS_END   8945664u

#define GLOBAL_AS __attribute__((address_space(1)))
#define LDS_AS    __attribute__((address_space(3)))

__device__ __forceinline__ void gload_lds16(const void* g, void* l) {
  __builtin_amdgcn_global_load_lds((const GLOBAL_AS void*)g, (LDS_AS void*)l, 16, 0, 0);
}

// -------- prep kernels --------
__global__ void k_bias(const float* __restrict__ a, const float* __restrict__ b,
                       float* __restrict__ d, int n) {
  int i = blockIdx.x * blockDim.x + threadIdx.x;
  if (i < n) d[i] = a[i] + b[i];
}

// Write W = [Wih | Whh] (row g, col k) in MFMA fragment order:
// dst[hg][kc][n][lane][8] with g = n*512 + hg*16 + (lane&15), k = kc*32 + (lane>>4)*8 + e
__global__ void k_wfrag(const float* __restrict__ wih, const float* __restrict__ whh,
                        _Float16* __restrict__ dst, int KX) {
  const int kc = blockIdx.x, hg = blockIdx.y, nch = gridDim.x;
  const int n = threadIdx.x >> 6, lane = threadIdx.x & 63;
  const int g  = n*512 + hg*16 + (lane & 15);
  const int k0 = kc*32 + (lane >> 4)*8;
  const float* src = (k0 < KX) ? (wih + (size_t)g*KX + k0) : (whh + (size_t)g*512 + (k0 - KX));
  float4 u0 = *(const float4*)src;
  float4 u1 = *(const float4*)(src + 4);
  half8 v;
  v[0]=(_Float16)u0.x; v[1]=(_Float16)u0.y; v[2]=(_Float16)u0.z; v[3]=(_Float16)u0.w;
  v[4]=(_Float16)u1.x; v[5]=(_Float16)u1.y; v[6]=(_Float16)u1.z; v[7]=(_Float16)u1.w;
  *(half8*)(dst + ((((size_t)hg*nch + kc)*4 + n)*64 + lane)*8) = v;
}

// -------- sync helpers (device-scope, per-(t,bx) counters) --------
__device__ __forceinline__ void sync_wait(int* p, int target) {
  if (threadIdx.x == 0) {
    while (__hip_atomic_load(p, __ATOMIC_RELAXED, __HIP_MEMORY_SCOPE_AGENT) < target)
      __builtin_amdgcn_s_sleep(2);
  }
  __syncthreads();
  __threadfence();   // acquire: invalidate stale L1/L2 before reading h
}
__device__ __forceinline__ void sync_pub(int* p) {
  __syncthreads();   // barrier drains each wave's vmcnt -> all h stores done
  if (threadIdx.x == 0) { __threadfence(); atomicAdd(p, 1); }   // release
}

// -------- K-chunk compute: 2 A-frags (wave's 2 m-tiles) x 4 B-frags (gate types) --------
__device__ __forceinline__ void chunk_mfma(const _Float16* ring, int buf, const _Float16* wres,
                                           int kcb, int rb0, int fko, int lane, floatx4 acc[2][4]) {
  const _Float16* rb = ring + buf*4096;
  const int rb1 = rb0 + 16;
  half8 a0 = *(const half8*)(rb + rb0*32 + (fko ^ (rb0 & 3) ^ ((rb0 >> 2) & 3))*8);
  half8 a1 = *(const half8*)(rb + rb1*32 + (fko ^ (rb1 & 3) ^ ((rb1 >> 2) & 3))*8);
  const _Float16* bb = wres + (size_t)kcb*2048 + lane*8;
  #pragma unroll
  for (int n = 0; n < 4; ++n) {
    half8 b = *(const half8*)(bb + n*512);
    acc[0][n] = __builtin_amdgcn_mfma_f32_16x16x32_f16(a0, b, acc[0][n], 0, 0, 0);
    acc[1][n] = __builtin_amdgcn_mfma_f32_16x16x32_f16(a1, b, acc[1][n], 0, 0, 0);
  }
}

// -------- pipelined K loop: reg-staged A, 3-slot LDS ring, lookahead 2 --------
template<int NC>
__device__ __forceinline__ void kloop_pipe(
    const _Float16* a0lo, const _Float16* a0hi,   // slot0 src base: kc<split / kc>=split (pre-adjusted)
    const _Float16* a1lo, const _Float16* a1hi,   // slot1
    int split, int kcb0,
    _Float16* ring, int lo0, int lo1,
    const _Float16* wres, int rb0, int fko, int lane, floatx4 acc[2][4])
{
  half8 pa[NC], pb[NC];
  auto LD = [&](int kc) {
    const _Float16* pA = (kc < split) ? a0lo : a0hi;
    const _Float16* pB = (kc < split) ? a1lo : a1hi;
    pa[kc] = *(const half8*)(pA + kc*32);
    pb[kc] = *(const half8*)(pB + kc*32);
  };
  auto DSW = [&](int kc) {
    _Float16* d = ring + (kc % 3)*4096;
    *(half8*)(d + lo0) = pa[kc];
    *(half8*)(d + lo1) = pb[kc];
  };
  LD(0); DSW(0);
  if (NC > 1) LD(1);
  #pragma unroll
  for (int kc = 0; kc < NC; ++kc) {
    if (kc + 2 < NC) LD(kc + 2);                       // issue early (hide L3 latency)
    chunk_mfma(ring, kc % 3, wres, kcb0 + kc, rb0, fko, lane, acc);
    if (kc + 1 < NC) DSW(kc + 1);                      // write late (load has been in flight ~2 chunks)
  }
}

// -------- LSTM elementwise epilogue (gates in-lane: n-tile == gate type) --------
__device__ __forceinline__ void cell_epilogue(const floatx4 acc[2][4], float* creg, float* hnv,
    float b_i, float b_f, float b_g, float b_o,
    _Float16* __restrict__ hout, int rowbase, int lane, int hcol)
{
  #pragma unroll
  for (int ci = 0; ci < 8; ++ci) {
    const int ml = ci >> 2, q = ci & 3;
    float iv = acc[ml][0][q] + b_i;
    float fv = acc[ml][1][q] + b_f;
    float gv = acc[ml][2][q] + b_g;
    float ov = acc[ml][3][q] + b_o;
    float ig = 1.f/(1.f+__expf(-iv));
    float fg = 1.f/(1.f+__expf(-fv));
    float og = 1.f/(1.f+__expf(-ov));
    float tg = 1.f - 2.f/(__expf(2.f*gv)+1.f);
    float cn = fg*creg[ci] + ig*tg;
    creg[ci] = cn;
    float tc = 1.f - 2.f/(__expf(2.f*cn)+1.f);
    float hv = og*tc;
    hnv[ci] = hv;
    int rowc = rowbase + ml*16 + (lane >> 4)*4 + q;
    hout[(size_t)rowc*HID + hcol] = (_Float16)hv;
  }
}

// -------- persistent kernel: blocks 0..127 = cell1, 128..255 = cell2 --------
__global__ __launch_bounds__(256, 1)
void lstm_persist(const float* __restrict__ sig,
                  const _Float16* __restrict__ w1f, const _Float16* __restrict__ w2f,
                  const float* __restrict__ bias1, const float* __restrict__ bias2,
                  _Float16* __restrict__ h1b, _Float16* __restrict__ h2b,
                  int* __restrict__ cnt1, int* __restrict__ cnt2,
                  const float* __restrict__ Wlin, const float* __restrict__ blin,
                  float* __restrict__ out)
{
  __shared__ __align__(16) char smem[SMEM_B];
  const int tid = threadIdx.x, lane = tid & 63, w = tid >> 6;
  const int gid = blockIdx.x;
  const bool g2 = gid >= 128;
  const int lg = g2 ? gid - 128 : gid;
  const int bx = lg >> 5, hg = lg & 31;   // 4 batch groups of 128 rows x 32 hcol groups of 16

  _Float16* wres = (_Float16*)smem;
  _Float16* ring = (_Float16*)(smem + (g2 ? W2RES_B : W1RES_B));

  // ---- W slice -> LDS once (frag order is linear: conflict-free forever after) ----
  {
    const _Float16* wsrc = g2 ? (w2f + (size_t)hg * (NCH2*4*64*8))
                              : (w1f + (size_t)hg * (NCH1*4*64*8));
    const int nj = g2 ? (W2RES_B/4096) : (W1RES_B/4096);
    for (int j = 0; j < nj; ++j) {
      char* dst = smem + ((size_t)j*256 + w*64) * 16;     // wave-uniform base
      gload_lds16(wsrc + ((size_t)j*256 + tid)*8, dst);
    }
  }
  __syncthreads();

  // ---- per-lane constants ----
  const int hcol = hg*16 + (lane & 15);
  const float* bias = g2 ? bias2 : bias1;
  const float b_i = bias[hcol], b_f = bias[512+hcol], b_g = bias[1024+hcol], b_o = bias[1536+hcol];
  float wl0 = 0.f, wl1 = 0.f, bl0 = 0.f, bl1 = 0.f;
  if (g2) { wl0 = Wlin[hcol]; wl1 = Wlin[512+hcol]; bl0 = blin[0]; bl1 = blin[1]; }

  // staging slots (wave self-stages its own 32 rows; swizzle matches frag read)
  const int r0 = 32*w + (lane >> 2), r1 = r0 + 16;
  const int ss = lane & 3;
  const int ko0 = ss ^ (r0 & 3) ^ ((r0 >> 2) & 3);
  const int ko1 = ss ^ (r1 & 3) ^ ((r1 >> 2) & 3);
  const int lo0 = r0*32 + ss*8, lo1 = r1*32 + ss*8;     // LDS half-offsets
  const int rowg0 = bx*128 + r0, rowg1 = bx*128 + r1;
  const int hofs0 = rowg0*512 + ko0*8, hofs1 = rowg1*512 + ko1*8;

  // frag read params
  const int rb0 = 32*w + (lane & 15);
  const int fko = lane >> 4;
  const int rowbase = bx*128 + 32*w;

  float creg[8];
  #pragma unroll
  for (int i = 0; i < 8; ++i) creg[i] = 0.f;

  for (int t = 0; t < TSTEPS; ++t) {
    floatx4 acc[2][4];
    #pragma unroll
    for (int a = 0; a < 2; ++a)
      #pragma unroll
      for (int b = 0; b < 4; ++b) acc[a][b] = (floatx4){0.f, 0.f, 0.f, 0.f};

    const int pin = t & 1, pout = (t + 1) & 1;

    if (!g2) {
      // ---- phase X (x @ Wih1, K=128): independent of h -> run BEFORE the waits ----
      const float* sigt = sig + (size_t)t * (BATCH*FEAT);
      #pragma unroll
      for (int kc = 0; kc < 4; ++kc) {
        const float* x0 = sigt + rowg0*128 + kc*32 + ko0*8;
        const float* x1 = sigt + rowg1*128 + kc*32 + ko1*8;
        float4 u0 = *(const float4*)x0, u1 = *(const float4*)(x0 + 4);
        float4 u2 = *(const float4*)x1, u3 = *(const float4*)(x1 + 4);
        half8 v0, v1;
        v0[0]=(_Float16)u0.x; v0[1]=(_Float16)u0.y; v0[2]=(_Float16)u0.z; v0[3]=(_Float16)u0.w;
        v0[4]=(_Float16)u1.x; v0[5]=(_Float16)u1.y; v0[6]=(_Float16)u1.z; v0[7]=(_Float16)u1.w;
        v1[0]=(_Float16)u2.x; v1[1]=(_Float16)u2.y; v1[2]=(_Float16)u2.z; v1[3]=(_Float16)u2.w;
        v1[4]=(_Float16)u3.x; v1[5]=(_Float16)u3.y; v1[6]=(_Float16)u3.z; v1[7]=(_Float16)u3.w;
        _Float16* d = ring + (kc % 3)*4096;
        *(half8*)(d + lo0) = v0;
        *(half8*)(d + lo1) = v1;
        chunk_mfma(ring, kc % 3, wres, kc, rb0, fko, lane, acc);
      }
      // ---- deps: h1(t-1) ready; WAR throttle: cell2 done with h1(t-2) ----
      if (t >= 1) sync_wait(&cnt1[(t-1)*4 + bx], 32);
      if (t >= 2) sync_wait(&cnt2[(t-2)*4 + bx], 32);
      // ---- phase H (h1 @ Whh1, K=512), pipelined ----
      const _Float16* hprev = h1b + (size_t)pin * (BATCH*HID);
      kloop_pipe<16>(hprev + hofs0, hprev + hofs0,
                     hprev + hofs1, hprev + hofs1,
                     16, 4, ring, lo0, lo1, wres, rb0, fko, lane, acc);
      // ---- epilogue + publish ----
      _Float16* hout = h1b + (size_t)pout * (BATCH*HID);
      float hnv[8];
      cell_epilogue(acc, creg, hnv, b_i, b_f, b_g, b_o, hout, rowbase, lane, hcol);
      sync_pub(&cnt1[t*4 + bx]);
    } else {
      // ---- deps: h1(t) and h2(t-1) ----
      sync_wait(&cnt1[t*4 + bx], 32);
      if (t >= 1) sync_wait(&cnt2[(t-1)*4 + bx], 32);
      const _Float16* h1cur  = h1b + (size_t)pout * (BATCH*HID);
      const _Float16* h2prev = h2b + (size_t)pin  * (BATCH*HID);
      kloop_pipe<32>(h1cur + hofs0, h2prev + hofs0 - 16*32,
                     h1cur + hofs1, h2prev + hofs1 - 16*32,
                     16, 0, ring, lo0, lo1, wres, rb0, fko, lane, acc);
      _Float16* hout = h2b + (size_t)pout * (BATCH*HID);
      float hnv[8];
      cell_epilogue(acc, creg, hnv, b_i, b_f, b_g, b_o, hout, rowbase, lane, hcol);
      sync_pub(&cnt2[t*4 + bx]);
      // ---- out = h2 @ Wlin^T + blin (shfl-reduce over the block's 16 hcols) ----
      #pragma unroll
      for (int ci = 0; ci < 8; ++ci) {
        float v0 = hnv[ci]*wl0, v1 = hnv[ci]*wl1;
        #pragma unroll
        for (int m = 8; m >= 1; m >>= 1) { v0 += __shfl_xor(v0, m); v1 += __shfl_xor(v1, m); }
        if ((lane & 15) == 0) {
          if (hg == 0) { v0 += bl0; v1 += bl1; }
          const int rowc = rowbase + (ci >> 2)*16 + (lane >> 4)*4 + (ci & 3);
          atomicAdd(&out[(size_t)rowc*(TSTEPS*2) + t*2 + 0], v0);
          atomicAdd(&out[(size_t)rowc*(TSTEPS*2) + t*2 + 1], v1);
        }
      }
    }
  }
}

// ---------------- host ----------------
extern "C" void kernel_launch(void* const* d_in, const int* in_sizes, int n_in,
                              void* d_out, int out_size, void* d_ws, size_t ws_size,
                              hipStream_t stream)
{
  const float* signal = (const float*)d_in[0];
  const float* Wih1 = (const float*)d_in[1];
  const float* Whh1 = (const float*)d_in[2];
  const float* bih1 = (const float*)d_in[3];
  const float* bhh1 = (const float*)d_in[4];
  const float* Wih2 = (const float*)d_in[5];
  const float* Whh2 = (const float*)d_in[6];
  const float* bih2 = (const float*)d_in[7];
  const float* bhh2 = (const float*)d_in[8];
  const float* Wlin = (const float*)d_in[9];
  const float* blin = (const float*)d_in[10];

  char* ws = (char*)d_ws;
  _Float16* w1f = (_Float16*)(ws + OFF_W1F);
  _Float16* w2f = (_Float16*)(ws + OFF_W2F);
  float* b1 = (float*)(ws + OFF_B1);
  float* b2 = (float*)(ws + OFF_B2);
  _Float16* h1 = (_Float16*)(ws + OFF_H1);
  _Float16* h2 = (_Float16*)(ws + OFF_H2);
  int* cnt1 = (int*)(ws + OFF_CNT1);
  int* cnt2 = (int*)(ws + OFF_CNT2);
  float* out = (float*)d_out;

  // zero h parity buffers + counters (contiguous) and output
  hipMemsetAsync(ws + OFF_H1, 0, (size_t)(WS_END - OFF_H1), stream);
  hipMemsetAsync(d_out, 0, (size_t)out_size * 4, stream);

  // prep: fragment-ordered f16 weights + fused biases
  k_wfrag<<<dim3(NCH1, 32), 256, 0, stream>>>(Wih1, Whh1, w1f, FEAT);
  k_wfrag<<<dim3(NCH2, 32), 256, 0, stream>>>(Wih2, Whh2, w2f, HID);
  k_bias<<<(2048 + 255) / 256, 256, 0, stream>>>(bih1, bhh1, b1, 2048);
  k_bias<<<(2048 + 255) / 256, 256, 0, stream>>>(bih2, bhh2, b2, 2048);

  void* args[] = { (void*)&signal, (void*)&w1f, (void*)&w2f, (void*)&b1, (void*)&b2,
                   (void*)&h1, (void*)&h2, (void*)&cnt1, (void*)&cnt2,
                   (void*)&Wlin, (void*)&blin, (void*)&out };
  hipLaunchCooperativeKernel((void*)lstm_persist, dim3(256), dim3(256), args, 0, stream);
}